// Round 1
// baseline (285.281 us; speedup 1.0000x reference)
//
#include <hip/hip_runtime.h>
#include <hip/hip_bf16.h>

typedef __attribute__((ext_vector_type(4))) float f4;
typedef __attribute__((ext_vector_type(8))) short s8;

#define MFMA16(a,b,c) __builtin_amdgcn_mfma_f32_16x16x32_bf16((a),(b),(c),0,0,0)

__device__ __forceinline__ unsigned short f2bf(float x){
  union { float f; unsigned u; } v; v.f = x;
  return (unsigned short)((v.u + 0x7fffu + ((v.u >> 16) & 1u)) >> 16);
}
__device__ __forceinline__ float bf2f(unsigned short h){
  union { unsigned u; float f; } v; v.u = ((unsigned)h) << 16;
  return v.f;
}
// B-fragment-linear index for mfma_f32_16x16x32_bf16:
// lane l holds B[k = kt*32 + (l>>4)*8 + j][col = ct*16 + (l&15)], j=0..7
__device__ __forceinline__ int fidx(int kk, int c, int nct){
  return ((((kk >> 5) * nct + (c >> 4)) << 6) + (((kk >> 3) & 3) * 16 + (c & 15))) * 8 + (kk & 7);
}

// ---------------- prep kernels: fold + bf16 fragment-shuffle weights ----------------
__global__ void prep1(const float* __restrict__ Ws, const float* __restrict__ Wa1,
                      const float* __restrict__ Wo,
                      unsigned short* __restrict__ Ws2f, unsigned short* __restrict__ Wof,
                      unsigned short* __restrict__ WsWa1f, float* __restrict__ WsWa1p){
  __shared__ float wrow[256];
  int i = blockIdx.x, t = threadIdx.x;
  wrow[t] = Ws[i*256 + t];
  __syncthreads();
  float a1 = 0.f;
  for (int t2 = 0; t2 < 256; ++t2) a1 += wrow[t2] * Ws[t2*256 + t];   // Ws2 = Ws@Ws
  Ws2f[fidx(i, t, 16)] = f2bf(a1);
  Wof[fidx(i, t, 16)]  = f2bf(Wo[i*256 + t]);
  if (t < 32){
    float a2 = 0.f;
    for (int t2 = 0; t2 < 256; ++t2) a2 += wrow[t2] * Wa1[t2*32 + t]; // WsWa1 = Ws@Wa1
    WsWa1p[i*32 + t] = a2;
    WsWa1f[fidx(i, t, 2)] = f2bf(a2);
  }
}

__global__ void prep2(const float* __restrict__ Wp2, const float* __restrict__ Wa2,
                      const float* __restrict__ Wa1, const float* __restrict__ bp2,
                      const float* __restrict__ ba1,
                      unsigned short* __restrict__ Wp2f, unsigned short* __restrict__ Wa2f,
                      float* __restrict__ Wp2Wa1, float* __restrict__ bh){
  int t = threadIdx.x;
  for (int j = 0; j < 32; ++j){
    int idx = t*32 + j; int kk = idx >> 8, c = idx & 255;
    Wp2f[fidx(kk, c, 16)] = f2bf(Wp2[idx]);
    Wa2f[fidx(kk, c, 16)] = f2bf(Wa2[idx]);
  }
  for (int j = 0; j < 4; ++j){                       // Wp2Wa1 = Wp2@Wa1 [32][32]
    int o = t*4 + j; int h1 = o >> 5, h2 = o & 31;
    float a = 0.f;
    for (int c = 0; c < 256; ++c) a += Wp2[h1*256 + c] * Wa1[c*32 + h2];
    Wp2Wa1[o] = a;
  }
  if (t < 32){                                       // bh = bp2@Wa1 + ba1
    float a = ba1[t];
    for (int c = 0; c < 256; ++c) a += bp2[c] * Wa1[c*32 + t];
    bh[t] = a;
  }
}

// ---------------- main fused kernel ----------------
#define NT 4          // n-rows per block
#define ROWS 64       // NT*16 (n,m) rows
#define STR_H 40      // LDS stride (ushorts) for 32-wide hidden tiles (80B, 16B-mult)

__global__ __launch_bounds__(256, 2) void attn_main(
  const float* __restrict__ q, const float* __restrict__ k,
  const float* __restrict__ pos, const int* __restrict__ mask,
  const float* __restrict__ Wp1, const float* __restrict__ bp1,
  const float* __restrict__ bp2, const float* __restrict__ bo,
  const float* __restrict__ WsWa1p, const float* __restrict__ Wp2Wa1,
  const float* __restrict__ bh,
  const unsigned short* __restrict__ Ws2f, const unsigned short* __restrict__ WsWa1f,
  const unsigned short* __restrict__ Wp2f, const unsigned short* __restrict__ Wa2f,
  const unsigned short* __restrict__ Wof,
  float* __restrict__ out)
{
  __shared__ unsigned short kA[ROWS * 256];   // bf16, XOR-swizzled, 32KB
  __shared__ unsigned short hB[ROWS * STR_H]; // relu'd hidden, bf16
  __shared__ unsigned short phB[ROWS * STR_H];// pos hidden, bf16
  __shared__ float sPre[ROWS * 32];           // phh - qh + bh
  __shared__ float qT[NT * 256];
  __shared__ float qhS[NT * 32];
  __shared__ unsigned short xT[16 * 256];     // bf16, swizzled; rows NT..15 zero
  __shared__ int mk[ROWS];

  const int t = threadIdx.x;
  const int lane = t & 63;
  const int w = t >> 6;
  const int bn0 = blockIdx.x * NT;
  const f4 z4 = {0.f, 0.f, 0.f, 0.f};

  // ---- Phase A: stage k->bf16 LDS (swizzled), q, pos->ph, mask, zero xT tail
  {
    const float* kb = k + (size_t)bn0 * 16 * 256;
    #pragma unroll
    for (int i = 0; i < 8; ++i) {
      int e = i * 2048 + t * 8;
      f4 a = *(const f4*)(kb + e);
      f4 b = *(const f4*)(kb + e + 4);
      s8 cv;
      cv[0] = (short)f2bf(a[0]); cv[1] = (short)f2bf(a[1]);
      cv[2] = (short)f2bf(a[2]); cv[3] = (short)f2bf(a[3]);
      cv[4] = (short)f2bf(b[0]); cv[5] = (short)f2bf(b[1]);
      cv[6] = (short)f2bf(b[2]); cv[7] = (short)f2bf(b[3]);
      int row = e >> 8, col = e & 255;
      int byte = row * 512 + ((col * 2) ^ ((row & 7) << 4));
      *(s8*)((char*)kA + byte) = cv;
    }
    ((f4*)qT)[t] = ((const f4*)(q + (size_t)bn0 * 256))[t];
    {
      int r = t >> 2, pp = t & 3;
      f4 pv = *(const f4*)(pos + (size_t)bn0 * 64 + r * 4);
      #pragma unroll
      for (int j = 0; j < 8; ++j) {
        int h = pp * 8 + j;
        float v = bp1[h] + pv[0]*Wp1[h] + pv[1]*Wp1[32+h] + pv[2]*Wp1[64+h] + pv[3]*Wp1[96+h];
        phB[r * STR_H + h] = f2bf(fmaxf(v, 0.f));
      }
    }
    if (t < ROWS) mk[t] = mask[(size_t)bn0 * 16 + t];
    #pragma unroll
    for (int j = 0; j < 12; ++j) xT[(NT + j) * 256 + t] = 0;
  }
  __syncthreads();

  // ---- Phase B: kh = k @ WsWa1 (MFMA, wave w = n-row w) + qh = q @ WsWa1 (VALU)
  f4 kh0 = z4, kh1 = z4;
  #pragma unroll
  for (int kt = 0; kt < 8; ++kt) {
    int row = w * 16 + (lane & 15);
    int byte = row * 512 + (((kt * 32 + (lane >> 4) * 8) * 2) ^ ((row & 7) << 4));
    s8 af = *(const s8*)((const char*)kA + byte);
    kh0 = MFMA16(af, *(const s8*)(WsWa1f + ((kt * 2 + 0) * 64 + lane) * 8), kh0);
    kh1 = MFMA16(af, *(const s8*)(WsWa1f + ((kt * 2 + 1) * 64 + lane) * 8), kh1);
  }
  if (t < 128) {
    int n = t >> 5, h = t & 31;
    float acc = 0.f;
    for (int kk = 0; kk < 256; ++kk) acc += qT[n * 256 + kk] * WsWa1p[kk * 32 + h];
    qhS[n * 32 + h] = acc;
  }
  __syncthreads();

  // ---- Phase C: sPre = ph@Wp2Wa1 - qh + bh
  {
    int r = t >> 2, pp = t & 3;
    float phr[32];
    #pragma unroll
    for (int h1 = 0; h1 < 32; ++h1) phr[h1] = bf2f(phB[r * STR_H + h1]);
    int n = r >> 4;
    #pragma unroll
    for (int j = 0; j < 8; ++j) {
      int h2 = pp * 8 + j;
      float acc = 0.f;
      #pragma unroll
      for (int h1 = 0; h1 < 32; ++h1) acc += phr[h1] * Wp2Wa1[h1 * 32 + h2];
      sPre[r * 32 + h2] = acc - qhS[n * 32 + h2] + bh[h2];
    }
  }
  __syncthreads();

  // ---- Phase D: h = relu(kh + sPre) -> hB
  #pragma unroll
  for (int ct = 0; ct < 2; ++ct)
    #pragma unroll
    for (int r = 0; r < 4; ++r) {
      int row = w * 16 + (lane >> 4) * 4 + r;
      int col = ct * 16 + (lane & 15);
      float hv = (ct == 0 ? kh0[r] : kh1[r]) + sPre[row * 32 + col];
      hB[row * STR_H + col] = f2bf(fmaxf(hv, 0.f));
    }
  __syncthreads();

  // ---- Phase E: column-split chunk loop. Wave w owns cols [w*64, w*64+64).
  #pragma unroll
  for (int cp = 0; cp < 2; ++cp) {
    int ct0 = w * 4 + cp * 2;
    f4 vac[4][2], pfac[4][2], aac[4][2];
    #pragma unroll
    for (int rt = 0; rt < 4; ++rt) { vac[rt][0]=z4; vac[rt][1]=z4; pfac[rt][0]=z4; pfac[rt][1]=z4; aac[rt][0]=z4; aac[rt][1]=z4; }
    // v = k @ Ws2 (K=256)
    #pragma unroll
    for (int kt = 0; kt < 8; ++kt) {
      s8 b0 = *(const s8*)(Ws2f + ((kt * 16 + ct0    ) * 64 + lane) * 8);
      s8 b1 = *(const s8*)(Ws2f + ((kt * 16 + ct0 + 1) * 64 + lane) * 8);
      #pragma unroll
      for (int rt = 0; rt < 4; ++rt) {
        int row = rt * 16 + (lane & 15);
        int byte = row * 512 + (((kt * 32 + (lane >> 4) * 8) * 2) ^ ((row & 7) << 4));
        s8 af = *(const s8*)((const char*)kA + byte);
        vac[rt][0] = MFMA16(af, b0, vac[rt][0]);
        vac[rt][1] = MFMA16(af, b1, vac[rt][1]);
      }
    }
    // posf = ph @ Wp2 ; a = h @ Wa2 (K=32 each)
    {
      s8 pb0 = *(const s8*)(Wp2f + ((ct0    ) * 64 + lane) * 8);
      s8 pb1 = *(const s8*)(Wp2f + ((ct0 + 1) * 64 + lane) * 8);
      s8 ab0 = *(const s8*)(Wa2f + ((ct0    ) * 64 + lane) * 8);
      s8 ab1 = *(const s8*)(Wa2f + ((ct0 + 1) * 64 + lane) * 8);
      #pragma unroll
      for (int rt = 0; rt < 4; ++rt) {
        int off = (rt * 16 + (lane & 15)) * STR_H + (lane >> 4) * 8;
        s8 pA = *(const s8*)(phB + off);
        s8 hA = *(const s8*)(hB + off);
        pfac[rt][0] = MFMA16(pA, pb0, pfac[rt][0]);
        pfac[rt][1] = MFMA16(pA, pb1, pfac[rt][1]);
        aac[rt][0] = MFMA16(hA, ab0, aac[rt][0]);
        aac[rt][1] = MFMA16(hA, ab1, aac[rt][1]);
      }
    }
    // mask -> softmax over m (4 regs + shfl_xor 16/32) -> x = sum_m w*(v+posf)
    #pragma unroll
    for (int rt = 0; rt < 4; ++rt) {
      int mb = rt * 16 + (lane >> 4) * 4;
      int m0 = mk[mb], m1 = mk[mb+1], m2 = mk[mb+2], m3 = mk[mb+3];
      #pragma unroll
      for (int cl = 0; cl < 2; ++cl) {
        int c = (ct0 + cl) * 16 + (lane & 15);
        float bp2c = bp2[c];
        float lg0 = m0 ? aac[rt][cl][0] : -1e9f;
        float lg1 = m1 ? aac[rt][cl][1] : -1e9f;
        float lg2 = m2 ? aac[rt][cl][2] : -1e9f;
        float lg3 = m3 ? aac[rt][cl][3] : -1e9f;
        float mx = fmaxf(fmaxf(lg0, lg1), fmaxf(lg2, lg3));
        mx = fmaxf(mx, __shfl_xor(mx, 16));
        mx = fmaxf(mx, __shfl_xor(mx, 32));
        float p0 = __expf(lg0 - mx), p1 = __expf(lg1 - mx);
        float p2 = __expf(lg2 - mx), p3 = __expf(lg3 - mx);
        float s = p0 + p1 + p2 + p3;
        float num = p0 * (vac[rt][cl][0] + pfac[rt][cl][0] + bp2c)
                  + p1 * (vac[rt][cl][1] + pfac[rt][cl][1] + bp2c)
                  + p2 * (vac[rt][cl][2] + pfac[rt][cl][2] + bp2c)
                  + p3 * (vac[rt][cl][3] + pfac[rt][cl][3] + bp2c);
        s   += __shfl_xor(s, 16);   s   += __shfl_xor(s, 32);
        num += __shfl_xor(num, 16); num += __shfl_xor(num, 32);
        if (lane < 16) {
          int byte = rt * 512 + ((c * 2) ^ ((rt & 7) << 4));
          *(unsigned short*)((char*)xT + byte) = f2bf(__fdividef(num, s));
        }
      }
    }
  }
  __syncthreads();

  // ---- Phase F: out = x @ Wo + bo (rows 0..NT-1 valid)
  f4 oac[4] = {z4, z4, z4, z4};
  #pragma unroll
  for (int kt = 0; kt < 8; ++kt) {
    int row = lane & 15;
    int byte = row * 512 + (((kt * 32 + (lane >> 4) * 8) * 2) ^ ((row & 7) << 4));
    s8 af = *(const s8*)((const char*)xT + byte);
    #pragma unroll
    for (int ci = 0; ci < 4; ++ci)
      oac[ci] = MFMA16(af, *(const s8*)(Wof + ((kt * 16 + w * 4 + ci) * 64 + lane) * 8), oac[ci]);
  }
  if (lane < 16) {
    #pragma unroll
    for (int ci = 0; ci < 4; ++ci) {
      int c = (w * 4 + ci) * 16 + lane;
      float bov = bo[c];
      #pragma unroll
      for (int r = 0; r < 4; ++r)
        out[(size_t)(bn0 + r) * 256 + c] = oac[ci][r] + bov;
    }
  }
}

extern "C" void kernel_launch(void* const* d_in, const int* in_sizes, int n_in,
                              void* d_out, int out_size, void* d_ws, size_t ws_size,
                              hipStream_t stream) {
  (void)in_sizes; (void)n_in; (void)out_size;
  const float* q   = (const float*)d_in[0];
  const float* k   = (const float*)d_in[1];
  const float* pos = (const float*)d_in[2];
  const int*   msk = (const int*)d_in[3];
  const float* Ws  = (const float*)d_in[4];
  const float* Wp1 = (const float*)d_in[5];
  const float* bp1 = (const float*)d_in[6];
  const float* Wp2 = (const float*)d_in[7];
  const float* bp2 = (const float*)d_in[8];
  const float* Wa1 = (const float*)d_in[9];
  const float* ba1 = (const float*)d_in[10];
  const float* Wa2 = (const float*)d_in[11];
  // d_in[12] = ba2: constant along softmax axis -> mathematically a no-op
  const float* Wo  = (const float*)d_in[13];
  const float* bo  = (const float*)d_in[14];

  if (ws_size < 348288) return;
  char* ws = (char*)d_ws;
  unsigned short* Ws2f   = (unsigned short*)(ws + 0);       // 131072 B
  unsigned short* Wof    = (unsigned short*)(ws + 131072);  // 131072 B
  unsigned short* WsWa1f = (unsigned short*)(ws + 262144);  // 16384 B
  unsigned short* Wp2f   = (unsigned short*)(ws + 278528);  // 16384 B
  unsigned short* Wa2f   = (unsigned short*)(ws + 294912);  // 16384 B
  float*          WsWa1p = (float*)(ws + 311296);           // 32768 B
  float*          Wp2Wa1 = (float*)(ws + 344064);           // 4096 B
  float*          bh     = (float*)(ws + 348160);           // 128 B

  prep1<<<dim3(256), dim3(256), 0, stream>>>(Ws, Wa1, Wo, Ws2f, Wof, WsWa1f, WsWa1p);
  prep2<<<dim3(1), dim3(256), 0, stream>>>(Wp2, Wa2, Wa1, bp2, ba1, Wp2f, Wa2f, Wp2Wa1, bh);
  attn_main<<<dim3(4096), dim3(256), 0, stream>>>(q, k, pos, msk, Wp1, bp1, bp2, bo,
                                                  WsWa1p, Wp2Wa1, bh,
                                                  Ws2f, WsWa1f, Wp2f, Wa2f, Wof,
                                                  (float*)d_out);
}

// Round 2
// 239.215 us; speedup vs baseline: 1.1926x; 1.1926x over previous
//
#include <hip/hip_runtime.h>
#include <hip/hip_bf16.h>

typedef __attribute__((ext_vector_type(4))) float f4;
typedef __attribute__((ext_vector_type(4))) int i4;
typedef __attribute__((ext_vector_type(8))) short s8;

#define MFMA16(a,b,c) __builtin_amdgcn_mfma_f32_16x16x32_bf16((a),(b),(c),0,0,0)

static __device__ __forceinline__ unsigned short f2bf(float x){
  union { float f; unsigned u; } v; v.f = x;
  return (unsigned short)((v.u + 0x7fffu + ((v.u >> 16) & 1u)) >> 16);
}
// B-fragment-linear index for mfma_f32_16x16x32_bf16:
// lane l holds B[k = kt*32 + (l>>4)*8 + j][col = ct*16 + (l&15)], j=0..7
__device__ __forceinline__ int fidx(int kk, int c, int nct){
  return ((((kk >> 5) * nct + (c >> 4)) << 6) + (((kk >> 3) & 3) * 16 + (c & 15))) * 8 + (kk & 7);
}

// ---------------- prep kernels: fold + bf16 fragment-shuffle weights ----------------
__global__ void prep1(const float* __restrict__ Ws, const float* __restrict__ Wa1,
                      const float* __restrict__ Wo,
                      unsigned short* __restrict__ Ws2f, unsigned short* __restrict__ Wof,
                      unsigned short* __restrict__ WsWa1f){
  __shared__ float wrow[256];
  int i = blockIdx.x, t = threadIdx.x;
  wrow[t] = Ws[i*256 + t];
  __syncthreads();
  float a1 = 0.f;
  for (int t2 = 0; t2 < 256; ++t2) a1 += wrow[t2] * Ws[t2*256 + t];   // Ws2 = Ws@Ws
  Ws2f[fidx(i, t, 16)] = f2bf(a1);
  Wof[fidx(i, t, 16)]  = f2bf(Wo[i*256 + t]);
  if (t < 32){
    float a2 = 0.f;
    for (int t2 = 0; t2 < 256; ++t2) a2 += wrow[t2] * Wa1[t2*32 + t]; // WsWa1 = Ws@Wa1
    WsWa1f[fidx(i, t, 2)] = f2bf(a2);
  }
}

__global__ void prep2(const float* __restrict__ Wp2, const float* __restrict__ Wa2,
                      const float* __restrict__ Wa1, const float* __restrict__ bp2,
                      const float* __restrict__ ba1,
                      unsigned short* __restrict__ Wp2f, unsigned short* __restrict__ Wa2f,
                      unsigned short* __restrict__ Wp2Wa1f, float* __restrict__ bh){
  int t = threadIdx.x;
  for (int j = 0; j < 32; ++j){
    int idx = t*32 + j; int kk = idx >> 8, c = idx & 255;
    Wp2f[fidx(kk, c, 16)] = f2bf(Wp2[idx]);
    Wa2f[fidx(kk, c, 16)] = f2bf(Wa2[idx]);
  }
  for (int j = 0; j < 4; ++j){                       // Wp2Wa1 = Wp2@Wa1 [32][32]
    int o = t*4 + j; int h1 = o >> 5, h2 = o & 31;
    float a = 0.f;
    for (int c = 0; c < 256; ++c) a += Wp2[h1*256 + c] * Wa1[c*32 + h2];
    Wp2Wa1f[fidx(h1, h2, 2)] = f2bf(a);
  }
  if (t < 32){                                       // bh = bp2@Wa1 + ba1
    float a = ba1[t];
    for (int c = 0; c < 256; ++c) a += bp2[c] * Wa1[c*32 + t];
    bh[t] = a;
  }
}

// ---------------- main fused kernel ----------------
#define STR_H 40   // LDS row stride (ushorts) for 32-wide hidden tiles

__global__ __launch_bounds__(256, 4) void attn_main(
  const float* __restrict__ q, const float* __restrict__ k,
  const float* __restrict__ pos, const int* __restrict__ mask,
  const float* __restrict__ Wp1, const float* __restrict__ bp1,
  const float* __restrict__ bp2, const float* __restrict__ bo,
  const float* __restrict__ bh,
  const unsigned short* __restrict__ Ws2f, const unsigned short* __restrict__ WsWa1f,
  const unsigned short* __restrict__ Wp2f, const unsigned short* __restrict__ Wa2f,
  const unsigned short* __restrict__ Wp2Wa1f, const unsigned short* __restrict__ Wof,
  float* __restrict__ out)
{
  __shared__ unsigned short phB[64 * STR_H]; // pos hidden, bf16, A-frag layout
  __shared__ unsigned short hB[64 * STR_H];  // relu'd attn hidden, bf16
  __shared__ unsigned short xT[16 * 256];    // x bf16, swizzled; rows 0..3 valid

  const int t = threadIdx.x;
  const int lane = t & 63;
  const int w = t >> 6;        // wave id = local n index
  const int lg = lane >> 4;    // lane group 0..3
  const int lr = lane & 15;    // lane row/col 0..15
  const int bn0 = blockIdx.x * 4;
  const int n = bn0 + w;       // this wave's flat n-row
  const f4 z4 = {0.f, 0.f, 0.f, 0.f};

  // ---- Phase A: pos-MLP -> phB (each wave writes its own 16 rows)
  {
    int r = t >> 2, pp = t & 3;
    f4 pv = *(const f4*)(pos + (size_t)bn0 * 64 + (size_t)r * 4);
    s8 pk;
    #pragma unroll
    for (int j = 0; j < 8; ++j){
      int h = pp * 8 + j;
      float v = bp1[h] + pv[0]*Wp1[h] + pv[1]*Wp1[32+h] + pv[2]*Wp1[64+h] + pv[3]*Wp1[96+h];
      pk[j] = (short)f2bf(fmaxf(v, 0.f));
    }
    *(s8*)(phB + r * STR_H + pp * 8) = pk;
  }
  __syncthreads();

  // ---- Phase B: load k fragments (pure k + (k-q)), kh = (k-q)@WsWa1 via MFMA
  const float* krow = k + (size_t)n * 4096 + (size_t)lr * 256;
  const float* qrow = q + (size_t)n * 256;
  const unsigned short* wa1b = WsWa1f + (size_t)lane * 8;
  s8 kfrag[8];
  f4 khac[2] = {z4, z4};
  #pragma unroll
  for (int kt = 0; kt < 8; ++kt){
    int c0 = kt * 32 + lg * 8;
    f4 ka = *(const f4*)(krow + c0);
    f4 kb = *(const f4*)(krow + c0 + 4);
    f4 qa = *(const f4*)(qrow + c0);
    f4 qb = *(const f4*)(qrow + c0 + 4);
    s8 kf, mf;
    #pragma unroll
    for (int j = 0; j < 4; ++j){
      kf[j]     = (short)f2bf(ka[j]);
      kf[4 + j] = (short)f2bf(kb[j]);
      mf[j]     = (short)f2bf(ka[j] - qa[j]);
      mf[4 + j] = (short)f2bf(kb[j] - qb[j]);
    }
    kfrag[kt] = kf;
    khac[0] = MFMA16(mf, *(const s8*)(wa1b + (size_t)(kt * 2 + 0) * 512), khac[0]);
    khac[1] = MFMA16(mf, *(const s8*)(wa1b + (size_t)(kt * 2 + 1) * 512), khac[1]);
  }

  // ---- Phase C: += ph@Wp2Wa1 (accumulates into khac)
  s8 phfrag = *(const s8*)(phB + (w * 16 + lr) * STR_H + lg * 8);
  {
    const unsigned short* wpwb = Wp2Wa1f + (size_t)lane * 8;
    khac[0] = MFMA16(phfrag, *(const s8*)(wpwb), khac[0]);
    khac[1] = MFMA16(phfrag, *(const s8*)(wpwb + 512), khac[1]);
  }

  // ---- Phase D: h = relu(khac + bh) -> hB (own rows)
  #pragma unroll
  for (int ct = 0; ct < 2; ++ct){
    float bhc = bh[ct * 16 + lr];
    #pragma unroll
    for (int r = 0; r < 4; ++r){
      int row = w * 16 + lg * 4 + r;
      hB[row * STR_H + ct * 16 + lr] = f2bf(fmaxf(khac[ct][r] + bhc, 0.f));
    }
  }
  __syncthreads();

  // ---- Phase E: per-ct {v, posf, logits} MFMA + masked softmax over m -> xT
  s8 hfrag = *(const s8*)(hB + (w * 16 + lr) * STR_H + lg * 8);
  i4 mv = *(const i4*)(mask + (size_t)n * 16 + lg * 4);
  const unsigned short* ws2b = Ws2f + (size_t)lane * 8;
  const unsigned short* wp2b = Wp2f + (size_t)lane * 8;
  const unsigned short* wa2b = Wa2f + (size_t)lane * 8;
  for (int ct = 0; ct < 16; ++ct){
    f4 vac = z4;
    #pragma unroll
    for (int kt = 0; kt < 8; ++kt)
      vac = MFMA16(kfrag[kt], *(const s8*)(ws2b + (size_t)(kt * 16 + ct) * 512), vac);
    f4 pf = MFMA16(phfrag, *(const s8*)(wp2b + (size_t)ct * 512), z4);
    f4 aa = MFMA16(hfrag,  *(const s8*)(wa2b + (size_t)ct * 512), z4);
    float bp2c = bp2[ct * 16 + lr];
    float lg0 = mv[0] ? aa[0] : -1e9f;
    float lg1 = mv[1] ? aa[1] : -1e9f;
    float lg2 = mv[2] ? aa[2] : -1e9f;
    float lg3 = mv[3] ? aa[3] : -1e9f;
    float mx = fmaxf(fmaxf(lg0, lg1), fmaxf(lg2, lg3));
    mx = fmaxf(mx, __shfl_xor(mx, 16));
    mx = fmaxf(mx, __shfl_xor(mx, 32));
    float p0 = __expf(lg0 - mx), p1 = __expf(lg1 - mx);
    float p2 = __expf(lg2 - mx), p3 = __expf(lg3 - mx);
    float den = p0 + p1 + p2 + p3;
    float num = p0 * (vac[0] + pf[0] + bp2c)
              + p1 * (vac[1] + pf[1] + bp2c)
              + p2 * (vac[2] + pf[2] + bp2c)
              + p3 * (vac[3] + pf[3] + bp2c);
    den += __shfl_xor(den, 16); den += __shfl_xor(den, 32);
    num += __shfl_xor(num, 16); num += __shfl_xor(num, 32);
    if (lane < 16){
      int byte = w * 512 + (((ct * 16 + lr) * 2) ^ (w << 4));
      *(unsigned short*)((char*)xT + byte) = f2bf(__fdividef(num, den));
    }
  }
  __syncthreads();

  // ---- Phase F: out = x @ Wo + bo (A rows 0..3 valid; garbage rows ignored)
  f4 oac[4] = {z4, z4, z4, z4};
  const unsigned short* wob = Wof + (size_t)lane * 8;
  #pragma unroll
  for (int kt = 0; kt < 8; ++kt){
    int byte = lr * 512 + (((kt * 32 + lg * 8) * 2) ^ ((lr & 7) << 4));
    s8 xf = *(const s8*)((const char*)xT + byte);
    #pragma unroll
    for (int ci = 0; ci < 4; ++ci)
      oac[ci] = MFMA16(xf, *(const s8*)(wob + (size_t)(kt * 16 + w * 4 + ci) * 512), oac[ci]);
  }
  if (lane < 16){
    #pragma unroll
    for (int ci = 0; ci < 4; ++ci){
      int c = (w * 4 + ci) * 16 + lr;
      float bov = bo[c];
      #pragma unroll
      for (int r = 0; r < 4; ++r)
        out[(size_t)(bn0 + r) * 256 + c] = oac[ci][r] + bov;
    }
  }
}

extern "C" void kernel_launch(void* const* d_in, const int* in_sizes, int n_in,
                              void* d_out, int out_size, void* d_ws, size_t ws_size,
                              hipStream_t stream) {
  (void)in_sizes; (void)n_in; (void)out_size;
  const float* q   = (const float*)d_in[0];
  const float* k   = (const float*)d_in[1];
  const float* pos = (const float*)d_in[2];
  const int*   msk = (const int*)d_in[3];
  const float* Ws  = (const float*)d_in[4];
  const float* Wp1 = (const float*)d_in[5];
  const float* bp1 = (const float*)d_in[6];
  const float* Wp2 = (const float*)d_in[7];
  const float* bp2 = (const float*)d_in[8];
  const float* Wa1 = (const float*)d_in[9];
  const float* ba1 = (const float*)d_in[10];
  const float* Wa2 = (const float*)d_in[11];
  // d_in[12] = ba2: constant along softmax axis -> mathematically a no-op
  const float* Wo  = (const float*)d_in[13];
  const float* bo  = (const float*)d_in[14];

  if (ws_size < 313472) return;
  char* ws = (char*)d_ws;
  unsigned short* Ws2f    = (unsigned short*)(ws + 0);       // 131072 B
  unsigned short* Wof     = (unsigned short*)(ws + 131072);  // 131072 B
  unsigned short* WsWa1f  = (unsigned short*)(ws + 262144);  // 16384 B
  unsigned short* Wp2f    = (unsigned short*)(ws + 278528);  // 16384 B
  unsigned short* Wa2f    = (unsigned short*)(ws + 294912);  // 16384 B
  unsigned short* Wp2Wa1f = (unsigned short*)(ws + 311296);  // 2048 B
  float*          bh      = (float*)(ws + 313344);           // 128 B

  prep1<<<dim3(256), dim3(256), 0, stream>>>(Ws, Wa1, Wo, Ws2f, Wof, WsWa1f);
  prep2<<<dim3(1), dim3(256), 0, stream>>>(Wp2, Wa2, Wa1, bp2, ba1, Wp2f, Wa2f, Wp2Wa1f, bh);
  attn_main<<<dim3(4096), dim3(256), 0, stream>>>(q, k, pos, msk, Wp1, bp1, bp2, bo, bh,
                                                  Ws2f, WsWa1f, Wp2f, Wa2f, Wp2Wa1f, Wof,
                                                  (float*)d_out);
}